// Round 6
// baseline (4886.589 us; speedup 1.0000x reference)
//
#include <hip/hip_runtime.h>

// ---------------------------------------------------------------------------
// Sparse MS-Deformable Attention, f32.
// Round 6: software-pipelined gather. The 32 (q,l,p) point-batches are fully
// unrolled and double-buffered: issue batch i+1's 8 dwordx4 BEFORE consuming
// batch i, with sched_barrier(0) pinning the order. Compiler then emits
// counted vmcnt(8) (never a full drain) -> loads continuously in flight.
// Round 5's asm value-fences forced a vmcnt(0) drain every point (loads in
// flight only ~35% of the time; 27 B/cy/CU vs ~64 L1 ceiling).
// GEMMs keep the register-blocked 8x4 tile.
// ---------------------------------------------------------------------------

typedef float f32x4 __attribute__((ext_vector_type(4)));

// Y[n, 0:M] = X[n, 0:256] @ W[256, M] + bias ; 32 rows/block, M threads,
// thread tile = 8 queries x 4 cols. Safe in-place (Y==X): block stages its
// 32 rows to LDS before any write.
template<int M>
__global__ __launch_bounds__(M)
void gemm_rb(const float* __restrict__ X, const float* __restrict__ W,
             const float* __restrict__ bias, float* __restrict__ Y) {
    __shared__ float xt[32 * 256];
    const int tid = threadIdx.x;
    const long row0 = (long)blockIdx.x * 32;
    const float4* src = (const float4*)(X + row0 * 256);
    float4* dst4 = (float4*)xt;
    for (int i = tid; i < 32 * 64; i += M) dst4[i] = src[i];
    __syncthreads();

    constexpr int CG = M / 4;
    const int cg = tid % CG, qg = tid / CG;    // qg in 0..3
    const int c0 = cg * 4, q0 = qg * 8;

    f32x4 acc[8];
#pragma unroll
    for (int qi = 0; qi < 8; ++qi) acc[qi] = (f32x4){0.f, 0.f, 0.f, 0.f};

    for (int k4 = 0; k4 < 64; ++k4) {
        f32x4 w[4];
#pragma unroll
        for (int r = 0; r < 4; ++r)
            w[r] = *(const f32x4*)&W[(size_t)(k4 * 4 + r) * M + c0];
        f32x4 xv[8];
#pragma unroll
        for (int qi = 0; qi < 8; ++qi)
            xv[qi] = *(const f32x4*)&xt[(q0 + qi) * 256 + k4 * 4];
#pragma unroll
        for (int qi = 0; qi < 8; ++qi) {
            f32x4 a = acc[qi];
            const f32x4 x = xv[qi];
            a.x = fmaf(x.x, w[0].x, a.x); a.y = fmaf(x.x, w[0].y, a.y);
            a.z = fmaf(x.x, w[0].z, a.z); a.w = fmaf(x.x, w[0].w, a.w);
            a.x = fmaf(x.y, w[1].x, a.x); a.y = fmaf(x.y, w[1].y, a.y);
            a.z = fmaf(x.y, w[1].z, a.z); a.w = fmaf(x.y, w[1].w, a.w);
            a.x = fmaf(x.z, w[2].x, a.x); a.y = fmaf(x.z, w[2].y, a.y);
            a.z = fmaf(x.z, w[2].z, a.z); a.w = fmaf(x.z, w[2].w, a.w);
            a.x = fmaf(x.w, w[3].x, a.x); a.y = fmaf(x.w, w[3].y, a.y);
            a.z = fmaf(x.w, w[3].z, a.z); a.w = fmaf(x.w, w[3].w, a.w);
            acc[qi] = a;
        }
    }

    const f32x4 bv = *(const f32x4*)&bias[c0];
#pragma unroll
    for (int qi = 0; qi < 8; ++qi) {
        f32x4 o = acc[qi];
        o.x += bv.x; o.y += bv.y; o.z += bv.z; o.w += bv.w;
        *(f32x4*)&Y[(size_t)(row0 + q0 + qi) * M + c0] = o;
    }
}

// 2 queries per block. 256 threads = 8 heads x 32 lanes; lane owns 8 raw
// channels. Softmax in LDS, then a fully-unrolled double-buffered gather
// pipeline over the 32 (q,l,p) point-batches, then fused W_val projection.
#define QPB 2
__global__ __launch_bounds__(256, 4)
void sample_agg_proj(const float* __restrict__ offs_all,
                     const float* __restrict__ logits_all,
                     const float* __restrict__ refpts,
                     const int* __restrict__ qoff, int n_off,
                     const float* __restrict__ v0, const float* __restrict__ v1,
                     const float* __restrict__ v2, const float* __restrict__ v3,
                     const float* __restrict__ W_val, const float* __restrict__ b_val,
                     float* __restrict__ val_out) {
    __shared__ float sOff[QPB][256];
    __shared__ float sAttn[QPB][128];
    __shared__ float sAgg[QPB][8][256];
    const int n0 = blockIdx.x * QPB;
    const int tid = threadIdx.x;

    if (tid < QPB * 64) ((f32x4*)sOff)[tid] = ((const f32x4*)(offs_all + (size_t)n0 * 256))[tid];
    else if (tid < QPB * 64 + QPB * 32)
        ((f32x4*)sAttn)[tid - QPB * 64] = ((const f32x4*)(logits_all + (size_t)n0 * 128))[tid - QPB * 64];
    __syncthreads();

    // softmax over 16 for each of QPB*8 (q,h) rows
    if (tid < QPB * 8) {
        float* row = &sAttn[tid >> 3][(tid & 7) * 16];
        float m = -1e30f;
#pragma unroll
        for (int i = 0; i < 16; ++i) m = fmaxf(m, row[i]);
        float s = 0.f;
#pragma unroll
        for (int i = 0; i < 16; ++i) { const float e = expf(row[i] - m); row[i] = e; s += e; }
        const float inv = 1.f / s;
#pragma unroll
        for (int i = 0; i < 16; ++i) row[i] *= inv;
    }
    __syncthreads();

    const int h = tid >> 5, g = tid & 31;
    const int g8 = g * 8;

    int b0 = 0, b1 = 0;
    for (int i = 1; i < n_off; ++i) {
        if (n0 >= qoff[i]) b0 = i;
        if (n0 + 1 >= qoff[i]) b1 = i;
    }
    const float4 rp = *(const float4*)(refpts + 2 * n0);  // n0 even -> 16B aligned
    const float ri0 = rp.x, rj0 = rp.y, ri1 = rp.z, rj1 = rp.w;

    float acc[QPB][8];
#pragma unroll
    for (int q = 0; q < QPB; ++q)
#pragma unroll
        for (int j = 0; j < 8; ++j) acc[q][j] = 0.f;

    f32x4 bufA[8], bufB[8];
    float wA[4], wB[4];

    // Descriptor + issue for point-batch IT (IT = q*16 + l*4 + p; all consts
    // after unroll). 8 dwordx4 loads into BUF, weights into WGT.
#define ISSUE(IT, BUF, WGT) do {                                               \
    const int q_ = (IT) >> 4, l_ = ((IT) >> 2) & 3, p_ = (IT) & 3;             \
    const int hw_ = (l_ == 0 ? 64 : (l_ == 1 ? 128 : (l_ == 2 ? 256 : 512)));  \
    const float sc_ = (float)hw_ * (1.0f / 512.0f);                            \
    const float* vbl_ = (l_ == 0 ? v0 : (l_ == 1 ? v1 : (l_ == 2 ? v2 : v3))); \
    const float* vb_ = vbl_ + (size_t)(q_ == 0 ? b0 : b1) * ((size_t)hw_ * hw_ * 256) + g8; \
    const float ri_ = (q_ == 0 ? ri0 : ri1), rj_ = (q_ == 0 ? rj0 : rj1);      \
    const int oi_ = ((h * 4 + l_) * 4 + p_) * 2;                               \
    const float fi_ = (ri_ + sOff[q_][oi_]) * sc_;                             \
    const float fj_ = (rj_ + sOff[q_][oi_ + 1]) * sc_;                         \
    const float a_ = sAttn[q_][(h * 4 + l_) * 4 + p_];                         \
    const float sci_ = fmaxf(fi_ - 0.5f, 0.f);                                 \
    const float scj_ = fmaxf(fj_ - 0.5f, 0.f);                                 \
    const float fli_ = floorf(sci_), flj_ = floorf(scj_);                      \
    const int i0_ = (int)fli_, j0_ = (int)flj_;                                \
    const float fri_ = sci_ - fli_, frj_ = scj_ - flj_;                        \
    const int i0c_ = min(i0_, hw_ - 1), i1c_ = min(i0_ + 1, hw_ - 1);          \
    const int j0c_ = min(j0_, hw_ - 1), j1c_ = min(j0_ + 1, hw_ - 1);          \
    const float uw_ = 1.f - fri_, lw_ = 1.f - frj_;                            \
    WGT[0] = uw_ * lw_ * a_;  WGT[1] = uw_ * frj_ * a_;                        \
    WGT[2] = fri_ * lw_ * a_; WGT[3] = fri_ * frj_ * a_;                       \
    const f32x4* cp0_ = (const f32x4*)(vb_ + (size_t)(i0c_ * hw_ + j0c_) * 256); \
    const f32x4* cp1_ = (const f32x4*)(vb_ + (size_t)(i0c_ * hw_ + j1c_) * 256); \
    const f32x4* cp2_ = (const f32x4*)(vb_ + (size_t)(i1c_ * hw_ + j0c_) * 256); \
    const f32x4* cp3_ = (const f32x4*)(vb_ + (size_t)(i1c_ * hw_ + j1c_) * 256); \
    BUF[0] = cp0_[0]; BUF[1] = cp0_[1]; BUF[2] = cp1_[0]; BUF[3] = cp1_[1];    \
    BUF[4] = cp2_[0]; BUF[5] = cp2_[1]; BUF[6] = cp3_[0]; BUF[7] = cp3_[1];    \
} while (0)

#define FMAGRP(BUF, WGT, IT) do {                                              \
    const int qf_ = (IT) >> 4;                                                 \
    _Pragma("unroll")                                                          \
    for (int cr_ = 0; cr_ < 4; ++cr_) {                                        \
        const float wv_ = WGT[cr_];                                            \
        const f32x4 u_ = BUF[cr_ * 2], x_ = BUF[cr_ * 2 + 1];                  \
        acc[qf_][0] = fmaf(wv_, u_.x, acc[qf_][0]);                            \
        acc[qf_][1] = fmaf(wv_, u_.y, acc[qf_][1]);                            \
        acc[qf_][2] = fmaf(wv_, u_.z, acc[qf_][2]);                            \
        acc[qf_][3] = fmaf(wv_, u_.w, acc[qf_][3]);                            \
        acc[qf_][4] = fmaf(wv_, x_.x, acc[qf_][4]);                            \
        acc[qf_][5] = fmaf(wv_, x_.y, acc[qf_][5]);                            \
        acc[qf_][6] = fmaf(wv_, x_.z, acc[qf_][6]);                            \
        acc[qf_][7] = fmaf(wv_, x_.w, acc[qf_][7]);                            \
    }                                                                          \
} while (0)

    ISSUE(0, bufA, wA);
#pragma unroll
    for (int it = 0; it < 32; it += 2) {
        if (it + 1 < 32) ISSUE(it + 1, bufB, wB);
        __builtin_amdgcn_sched_barrier(0);   // B issued before A consumed
        FMAGRP(bufA, wA, it);                // compiler emits vmcnt(8) here
        if (it + 2 < 32) ISSUE(it + 2, bufA, wA);
        __builtin_amdgcn_sched_barrier(0);
        FMAGRP(bufB, wB, it + 1);
        if (it + 1 == 15) {                  // q=0 done: free its acc regs
            f32x4* sa4 = (f32x4*)(&sAgg[0][h][g8]);
            sa4[0] = (f32x4){acc[0][0], acc[0][1], acc[0][2], acc[0][3]};
            sa4[1] = (f32x4){acc[0][4], acc[0][5], acc[0][6], acc[0][7]};
        }
    }
    {
        f32x4* sa4 = (f32x4*)(&sAgg[1][h][g8]);
        sa4[0] = (f32x4){acc[1][0], acc[1][1], acc[1][2], acc[1][3]};
        sa4[1] = (f32x4){acc[1][4], acc[1][5], acc[1][6], acc[1][7]};
    }
#undef ISSUE
#undef FMAGRP
    __syncthreads();

    // projection: out channel c2 = tid, head h2 = c2/32; W_val row loads
    // shared across the QPB queries.
    const int c2 = tid, h2 = tid >> 5;
    float s[QPB];
#pragma unroll
    for (int q = 0; q < QPB; ++q) s[q] = b_val[c2];
    for (int k4 = 0; k4 < 64; ++k4) {
        const float w0 = W_val[(k4 * 4 + 0) * 256 + c2];
        const float w1 = W_val[(k4 * 4 + 1) * 256 + c2];
        const float w2 = W_val[(k4 * 4 + 2) * 256 + c2];
        const float w3 = W_val[(k4 * 4 + 3) * 256 + c2];
#pragma unroll
        for (int q = 0; q < QPB; ++q) {
            const f32x4 av = ((const f32x4*)sAgg[q][h2])[k4];
            float t = s[q];
            t = fmaf(av.x, w0, t);
            t = fmaf(av.y, w1, t);
            t = fmaf(av.z, w2, t);
            t = fmaf(av.w, w3, t);
            s[q] = t;
        }
    }
#pragma unroll
    for (int q = 0; q < QPB; ++q)
        val_out[(size_t)(n0 + q) * 256 + c2] = s[q];
}

extern "C" void kernel_launch(void* const* d_in, const int* in_sizes, int n_in,
                              void* d_out, int out_size, void* d_ws, size_t ws_size,
                              hipStream_t stream) {
    const float* query  = (const float*)d_in[0];
    const int*   qoff   = (const int*)d_in[1];
    const float* refp   = (const float*)d_in[2];
    const float* v0     = (const float*)d_in[3];
    const float* v1     = (const float*)d_in[4];
    const float* v2     = (const float*)d_in[5];
    const float* v3     = (const float*)d_in[6];
    const float* W_off  = (const float*)d_in[7];
    const float* b_off  = (const float*)d_in[8];
    const float* W_attn = (const float*)d_in[9];
    const float* b_attn = (const float*)d_in[10];
    const float* W_val  = (const float*)d_in[11];
    const float* b_val  = (const float*)d_in[12];
    const float* W_out  = (const float*)d_in[13];
    const float* b_out  = (const float*)d_in[14];
    float* out = (float*)d_out;

    const int N = in_sizes[0] / 256;   // 16384
    const int n_off = in_sizes[1];     // 2

    float* P1off  = (float*)d_ws;                 // N*256 f32 (offsets)
    float* P1attn = P1off + (size_t)N * 256;      // N*128 f32 (attn logits)

    gemm_rb<256><<<N / 32, 256, 0, stream>>>(query, W_off, b_off, P1off);
    gemm_rb<128><<<N / 32, 128, 0, stream>>>(query, W_attn, b_attn, P1attn);
    // softmax fused into sample_agg_proj (reads logits).
    sample_agg_proj<<<N / QPB, 256, 0, stream>>>(P1off, P1attn, refp, qoff, n_off,
                                                 v0, v1, v2, v3, W_val, b_val, out);
    gemm_rb<256><<<N / 32, 256, 0, stream>>>(out, W_out, b_out, out);
}

// Round 7
// 2611.569 us; speedup vs baseline: 1.8711x; 1.8711x over previous
//
#include <hip/hip_runtime.h>

// ---------------------------------------------------------------------------
// Sparse MS-Deformable Attention, f32.
// Round 7: triple-buffered gather pipeline with NO sched_barrier walls.
// Round 6's sched_barrier(0) x32 caused a scratch spill cascade (9.7 GB
// writes/dispatch). Here ordering is enforced purely by dependences:
//   fence(k) ["+v" asm on buf k%3, volatile => fences totally ordered]
//   -> FMA(k) reads fence outputs
//   -> loads(k+3) write the SAME buffer (WAR: must follow FMA(k))
// Fences sit at CONSUME time, 3 groups after issue => compiler emits counted
// vmcnt(8), never a drain; 12 dwordx4 continuously in flight per lane.
// 64 groups = 2 queries x 4 levels x 4 points x 2 half-points (4 loads each).
// GEMMs keep the register-blocked 8x4 tile.
// ---------------------------------------------------------------------------

typedef float f32x4 __attribute__((ext_vector_type(4)));

// Y[n, 0:M] = X[n, 0:256] @ W[256, M] + bias ; 32 rows/block, M threads,
// thread tile = 8 queries x 4 cols. Safe in-place (Y==X): block stages its
// 32 rows to LDS before any write.
template<int M>
__global__ __launch_bounds__(M)
void gemm_rb(const float* __restrict__ X, const float* __restrict__ W,
             const float* __restrict__ bias, float* __restrict__ Y) {
    __shared__ float xt[32 * 256];
    const int tid = threadIdx.x;
    const long row0 = (long)blockIdx.x * 32;
    const float4* src = (const float4*)(X + row0 * 256);
    float4* dst4 = (float4*)xt;
    for (int i = tid; i < 32 * 64; i += M) dst4[i] = src[i];
    __syncthreads();

    constexpr int CG = M / 4;
    const int cg = tid % CG, qg = tid / CG;    // qg in 0..3
    const int c0 = cg * 4, q0 = qg * 8;

    f32x4 acc[8];
#pragma unroll
    for (int qi = 0; qi < 8; ++qi) acc[qi] = (f32x4){0.f, 0.f, 0.f, 0.f};

    for (int k4 = 0; k4 < 64; ++k4) {
        f32x4 w[4];
#pragma unroll
        for (int r = 0; r < 4; ++r)
            w[r] = *(const f32x4*)&W[(size_t)(k4 * 4 + r) * M + c0];
        f32x4 xv[8];
#pragma unroll
        for (int qi = 0; qi < 8; ++qi)
            xv[qi] = *(const f32x4*)&xt[(q0 + qi) * 256 + k4 * 4];
#pragma unroll
        for (int qi = 0; qi < 8; ++qi) {
            f32x4 a = acc[qi];
            const f32x4 x = xv[qi];
            a.x = fmaf(x.x, w[0].x, a.x); a.y = fmaf(x.x, w[0].y, a.y);
            a.z = fmaf(x.x, w[0].z, a.z); a.w = fmaf(x.x, w[0].w, a.w);
            a.x = fmaf(x.y, w[1].x, a.x); a.y = fmaf(x.y, w[1].y, a.y);
            a.z = fmaf(x.y, w[1].z, a.z); a.w = fmaf(x.y, w[1].w, a.w);
            a.x = fmaf(x.z, w[2].x, a.x); a.y = fmaf(x.z, w[2].y, a.y);
            a.z = fmaf(x.z, w[2].z, a.z); a.w = fmaf(x.z, w[2].w, a.w);
            a.x = fmaf(x.w, w[3].x, a.x); a.y = fmaf(x.w, w[3].y, a.y);
            a.z = fmaf(x.w, w[3].z, a.z); a.w = fmaf(x.w, w[3].w, a.w);
            acc[qi] = a;
        }
    }

    const f32x4 bv = *(const f32x4*)&bias[c0];
#pragma unroll
    for (int qi = 0; qi < 8; ++qi) {
        f32x4 o = acc[qi];
        o.x += bv.x; o.y += bv.y; o.z += bv.z; o.w += bv.w;
        *(f32x4*)&Y[(size_t)(row0 + q0 + qi) * M + c0] = o;
    }
}

// 2 queries per block. 256 threads = 8 heads x 32 lanes; lane owns 8 raw
// channels. Softmax in LDS, triple-buffered gather pipeline over 64 groups,
// then fused W_val projection.
#define QPB 2
__global__ __launch_bounds__(256, 4)
void sample_agg_proj(const float* __restrict__ offs_all,
                     const float* __restrict__ logits_all,
                     const float* __restrict__ refpts,
                     const int* __restrict__ qoff, int n_off,
                     const float* __restrict__ v0, const float* __restrict__ v1,
                     const float* __restrict__ v2, const float* __restrict__ v3,
                     const float* __restrict__ W_val, const float* __restrict__ b_val,
                     float* __restrict__ val_out) {
    __shared__ float sOff[QPB][256];
    __shared__ float sAttn[QPB][128];
    __shared__ float sAgg[QPB][8][256];
    const int n0 = blockIdx.x * QPB;
    const int tid = threadIdx.x;

    if (tid < QPB * 64) ((f32x4*)sOff)[tid] = ((const f32x4*)(offs_all + (size_t)n0 * 256))[tid];
    else if (tid < QPB * 64 + QPB * 32)
        ((f32x4*)sAttn)[tid - QPB * 64] = ((const f32x4*)(logits_all + (size_t)n0 * 128))[tid - QPB * 64];
    __syncthreads();

    // softmax over 16 for each of QPB*8 (q,h) rows
    if (tid < QPB * 8) {
        float* row = &sAttn[tid >> 3][(tid & 7) * 16];
        float m = -1e30f;
#pragma unroll
        for (int i = 0; i < 16; ++i) m = fmaxf(m, row[i]);
        float s = 0.f;
#pragma unroll
        for (int i = 0; i < 16; ++i) { const float e = expf(row[i] - m); row[i] = e; s += e; }
        const float inv = 1.f / s;
#pragma unroll
        for (int i = 0; i < 16; ++i) row[i] *= inv;
    }
    __syncthreads();

    const int h = tid >> 5, g = tid & 31;
    const int g8 = g * 8;

    int b0 = 0, b1 = 0;
    for (int i = 1; i < n_off; ++i) {
        if (n0 >= qoff[i]) b0 = i;
        if (n0 + 1 >= qoff[i]) b1 = i;
    }
    const float4 rp = *(const float4*)(refpts + 2 * n0);  // n0 even -> aligned

    float acc[QPB][8];
#pragma unroll
    for (int q = 0; q < QPB; ++q)
#pragma unroll
        for (int j = 0; j < 8; ++j) acc[q][j] = 0.f;

    // pipeline state: 3 load buffers (4 x dwordx4), rotating [2] descriptors
    f32x4 buf[3][4];
    float wgtb[2][4];
    const float* r0b[2];
    const float* r1b[2];
    int cj0b[2], cj1b[2];

    // Descriptor for global point P (0..31): P = q*16 + l*4 + p.
#define DESC(P) do {                                                           \
    const int q_ = (P) >> 4, l_ = ((P) >> 2) & 3, p_ = (P) & 3;                \
    const int hw_ = (l_ == 0 ? 64 : (l_ == 1 ? 128 : (l_ == 2 ? 256 : 512)));  \
    const float sc_ = (float)hw_ * (1.0f / 512.0f);                            \
    const float* vbl_ = (l_ == 0 ? v0 : (l_ == 1 ? v1 : (l_ == 2 ? v2 : v3))); \
    const float* vb_ = vbl_ + (size_t)(q_ == 0 ? b0 : b1) * ((size_t)hw_ * hw_ * 256) + g8; \
    const float ri_ = (q_ == 0 ? rp.x : rp.z), rj_ = (q_ == 0 ? rp.y : rp.w);  \
    const int oi_ = ((h * 4 + l_) * 4 + p_) * 2;                               \
    const float fi_ = (ri_ + sOff[q_][oi_]) * sc_;                             \
    const float fj_ = (rj_ + sOff[q_][oi_ + 1]) * sc_;                         \
    const float a_ = sAttn[q_][(h * 4 + l_) * 4 + p_];                         \
    const float sci_ = fmaxf(fi_ - 0.5f, 0.f);                                 \
    const float scj_ = fmaxf(fj_ - 0.5f, 0.f);                                 \
    const float fli_ = floorf(sci_), flj_ = floorf(scj_);                      \
    const int i0_ = (int)fli_, j0_ = (int)flj_;                                \
    const float fri_ = sci_ - fli_, frj_ = scj_ - flj_;                        \
    const int i0c_ = min(i0_, hw_ - 1), i1c_ = min(i0_ + 1, hw_ - 1);          \
    const int j0c_ = min(j0_, hw_ - 1), j1c_ = min(j0_ + 1, hw_ - 1);          \
    const float uw_ = 1.f - fri_, lw_ = 1.f - frj_;                            \
    wgtb[(P) & 1][0] = uw_ * lw_ * a_;  wgtb[(P) & 1][1] = uw_ * frj_ * a_;    \
    wgtb[(P) & 1][2] = fri_ * lw_ * a_; wgtb[(P) & 1][3] = fri_ * frj_ * a_;   \
    r0b[(P) & 1] = vb_ + (size_t)i0c_ * hw_ * 256;                             \
    r1b[(P) & 1] = vb_ + (size_t)i1c_ * hw_ * 256;                             \
    cj0b[(P) & 1] = j0c_ * 256; cj1b[(P) & 1] = j1c_ * 256;                    \
} while (0)

    // Issue group K (= point*2 + half) into buffer C: 4 dwordx4 loads.
#define ISSUE(K, C) do {                                                       \
    const int P_ = (K) >> 1, hf_ = (K) & 1, ix_ = P_ & 1;                      \
    const float* r_ = hf_ ? r1b[ix_] : r0b[ix_];                               \
    const f32x4* ca_ = (const f32x4*)(r_ + cj0b[ix_]);                         \
    const f32x4* cb_ = (const f32x4*)(r_ + cj1b[ix_]);                         \
    buf[C][0] = ca_[0]; buf[C][1] = ca_[1];                                    \
    buf[C][2] = cb_[0]; buf[C][3] = cb_[1];                                    \
} while (0)

    // Fence (forces counted vmcnt here) + consume group K from buffer C.
#define CONSUME(K, C) do {                                                     \
    asm volatile("" : "+v"(buf[C][0]), "+v"(buf[C][1]),                        \
                      "+v"(buf[C][2]), "+v"(buf[C][3]));                       \
    const int P_ = (K) >> 1, hf_ = (K) & 1, ix_ = P_ & 1, q_ = P_ >> 4;        \
    const float wA_ = wgtb[ix_][hf_ * 2 + 0];                                  \
    const float wB_ = wgtb[ix_][hf_ * 2 + 1];                                  \
    acc[q_][0] = fmaf(wA_, buf[C][0].x, acc[q_][0]);                           \
    acc[q_][1] = fmaf(wA_, buf[C][0].y, acc[q_][1]);                           \
    acc[q_][2] = fmaf(wA_, buf[C][0].z, acc[q_][2]);                           \
    acc[q_][3] = fmaf(wA_, buf[C][0].w, acc[q_][3]);                           \
    acc[q_][4] = fmaf(wA_, buf[C][1].x, acc[q_][4]);                           \
    acc[q_][5] = fmaf(wA_, buf[C][1].y, acc[q_][5]);                           \
    acc[q_][6] = fmaf(wA_, buf[C][1].z, acc[q_][6]);                           \
    acc[q_][7] = fmaf(wA_, buf[C][1].w, acc[q_][7]);                           \
    acc[q_][0] = fmaf(wB_, buf[C][2].x, acc[q_][0]);                           \
    acc[q_][1] = fmaf(wB_, buf[C][2].y, acc[q_][1]);                           \
    acc[q_][2] = fmaf(wB_, buf[C][2].z, acc[q_][2]);                           \
    acc[q_][3] = fmaf(wB_, buf[C][2].w, acc[q_][3]);                           \
    acc[q_][4] = fmaf(wB_, buf[C][3].x, acc[q_][4]);                           \
    acc[q_][5] = fmaf(wB_, buf[C][3].y, acc[q_][5]);                           \
    acc[q_][6] = fmaf(wB_, buf[C][3].z, acc[q_][6]);                           \
    acc[q_][7] = fmaf(wB_, buf[C][3].w, acc[q_][7]);                           \
} while (0)

    // prologue: 3 groups in flight
    DESC(0);
    ISSUE(0, 0);
    ISSUE(1, 1);
    DESC(1);
    ISSUE(2, 2);

#pragma unroll
    for (int k = 0; k < 64; ++k) {
        const int c = k % 3;
        CONSUME(k, c);
        if (k + 3 < 64) {
            if (((k + 3) & 1) == 0) DESC((k + 3) >> 1);
            ISSUE(k + 3, c);
        }
        if (k == 31) {   // q=0 complete
            f32x4* sa4 = (f32x4*)(&sAgg[0][h][g8]);
            sa4[0] = (f32x4){acc[0][0], acc[0][1], acc[0][2], acc[0][3]};
            sa4[1] = (f32x4){acc[0][4], acc[0][5], acc[0][6], acc[0][7]};
        }
    }
    {
        f32x4* sa4 = (f32x4*)(&sAgg[1][h][g8]);
        sa4[0] = (f32x4){acc[1][0], acc[1][1], acc[1][2], acc[1][3]};
        sa4[1] = (f32x4){acc[1][4], acc[1][5], acc[1][6], acc[1][7]};
    }
#undef DESC
#undef ISSUE
#undef CONSUME
    __syncthreads();

    // projection: out channel c2 = tid, head h2 = c2/32; W_val row loads
    // shared across the QPB queries.
    const int c2 = tid, h2 = tid >> 5;
    float s[QPB];
#pragma unroll
    for (int q = 0; q < QPB; ++q) s[q] = b_val[c2];
    for (int k4 = 0; k4 < 64; ++k4) {
        const float w0 = W_val[(k4 * 4 + 0) * 256 + c2];
        const float w1 = W_val[(k4 * 4 + 1) * 256 + c2];
        const float w2 = W_val[(k4 * 4 + 2) * 256 + c2];
        const float w3 = W_val[(k4 * 4 + 3) * 256 + c2];
#pragma unroll
        for (int q = 0; q < QPB; ++q) {
            const f32x4 av = ((const f32x4*)sAgg[q][h2])[k4];
            float t = s[q];
            t = fmaf(av.x, w0, t);
            t = fmaf(av.y, w1, t);
            t = fmaf(av.z, w2, t);
            t = fmaf(av.w, w3, t);
            s[q] = t;
        }
    }
#pragma unroll
    for (int q = 0; q < QPB; ++q)
        val_out[(size_t)(n0 + q) * 256 + c2] = s[q];
}

extern "C" void kernel_launch(void* const* d_in, const int* in_sizes, int n_in,
                              void* d_out, int out_size, void* d_ws, size_t ws_size,
                              hipStream_t stream) {
    const float* query  = (const float*)d_in[0];
    const int*   qoff   = (const int*)d_in[1];
    const float* refp   = (const float*)d_in[2];
    const float* v0     = (const float*)d_in[3];
    const float* v1     = (const float*)d_in[4];
    const float* v2     = (const float*)d_in[5];
    const float* v3     = (const float*)d_in[6];
    const float* W_off  = (const float*)d_in[7];
    const float* b_off  = (const float*)d_in[8];
    const float* W_attn = (const float*)d_in[9];
    const float* b_attn = (const float*)d_in[10];
    const float* W_val  = (const float*)d_in[11];
    const float* b_val  = (const float*)d_in[12];
    const float* W_out  = (const float*)d_in[13];
    const float* b_out  = (const float*)d_in[14];
    float* out = (float*)d_out;

    const int N = in_sizes[0] / 256;   // 16384
    const int n_off = in_sizes[1];     // 2

    float* P1off  = (float*)d_ws;                 // N*256 f32 (offsets)
    float* P1attn = P1off + (size_t)N * 256;      // N*128 f32 (attn logits)

    gemm_rb<256><<<N / 32, 256, 0, stream>>>(query, W_off, b_off, P1off);
    gemm_rb<128><<<N / 32, 128, 0, stream>>>(query, W_attn, b_attn, P1attn);
    // softmax fused into sample_agg_proj (reads logits).
    sample_agg_proj<<<N / QPB, 256, 0, stream>>>(P1off, P1attn, refp, qoff, n_off,
                                                 v0, v1, v2, v3, W_val, b_val, out);
    gemm_rb<256><<<N / 32, 256, 0, stream>>>(out, W_out, b_out, out);
}

// Round 8
// 614.600 us; speedup vs baseline: 7.9509x; 4.2492x over previous
//
#include <hip/hip_runtime.h>

// ---------------------------------------------------------------------------
// Sparse MS-Deformable Attention, f32.
// Round 8: back to round-5's proven fence-per-point structure (52 VGPR,
// spill-free), with the occupancy lever applied correctly:
//  - NO __launch_bounds__ on the sampler: rounds 3/5 showed (256,4) caps
//    occupancy at ~44% (allocation padded to 128-reg budget), while a hard
//    (256,8) contract makes the allocator spill (rounds 4/6/7). With no
//    bound, allocation ~= usage (~55-60) -> 8 waves/SIMD naturally.
//  - Per-POINT descriptors (round 5 held a full level's 4 descriptors live,
//    ~32 extra regs) and a "memory" clobber on the fence so next-point loads
//    cannot hoist across and re-inflate pressure.
// GEMMs keep the register-blocked 8x4 tile.
// ---------------------------------------------------------------------------

typedef float f32x4 __attribute__((ext_vector_type(4)));

// Y[n, 0:M] = X[n, 0:256] @ W[256, M] + bias ; 32 rows/block, M threads,
// thread tile = 8 queries x 4 cols. Safe in-place (Y==X): block stages its
// 32 rows to LDS before any write.
template<int M>
__global__ __launch_bounds__(M)
void gemm_rb(const float* __restrict__ X, const float* __restrict__ W,
             const float* __restrict__ bias, float* __restrict__ Y) {
    __shared__ float xt[32 * 256];
    const int tid = threadIdx.x;
    const long row0 = (long)blockIdx.x * 32;
    const float4* src = (const float4*)(X + row0 * 256);
    float4* dst4 = (float4*)xt;
    for (int i = tid; i < 32 * 64; i += M) dst4[i] = src[i];
    __syncthreads();

    constexpr int CG = M / 4;
    const int cg = tid % CG, qg = tid / CG;    // qg in 0..3
    const int c0 = cg * 4, q0 = qg * 8;

    f32x4 acc[8];
#pragma unroll
    for (int qi = 0; qi < 8; ++qi) acc[qi] = (f32x4){0.f, 0.f, 0.f, 0.f};

    for (int k4 = 0; k4 < 64; ++k4) {
        f32x4 w[4];
#pragma unroll
        for (int r = 0; r < 4; ++r)
            w[r] = *(const f32x4*)&W[(size_t)(k4 * 4 + r) * M + c0];
        f32x4 xv[8];
#pragma unroll
        for (int qi = 0; qi < 8; ++qi)
            xv[qi] = *(const f32x4*)&xt[(q0 + qi) * 256 + k4 * 4];
#pragma unroll
        for (int qi = 0; qi < 8; ++qi) {
            f32x4 a = acc[qi];
            const f32x4 x = xv[qi];
            a.x = fmaf(x.x, w[0].x, a.x); a.y = fmaf(x.x, w[0].y, a.y);
            a.z = fmaf(x.x, w[0].z, a.z); a.w = fmaf(x.x, w[0].w, a.w);
            a.x = fmaf(x.y, w[1].x, a.x); a.y = fmaf(x.y, w[1].y, a.y);
            a.z = fmaf(x.y, w[1].z, a.z); a.w = fmaf(x.y, w[1].w, a.w);
            a.x = fmaf(x.z, w[2].x, a.x); a.y = fmaf(x.z, w[2].y, a.y);
            a.z = fmaf(x.z, w[2].z, a.z); a.w = fmaf(x.z, w[2].w, a.w);
            a.x = fmaf(x.w, w[3].x, a.x); a.y = fmaf(x.w, w[3].y, a.y);
            a.z = fmaf(x.w, w[3].z, a.z); a.w = fmaf(x.w, w[3].w, a.w);
            acc[qi] = a;
        }
    }

    const f32x4 bv = *(const f32x4*)&bias[c0];
#pragma unroll
    for (int qi = 0; qi < 8; ++qi) {
        f32x4 o = acc[qi];
        o.x += bv.x; o.y += bv.y; o.z += bv.z; o.w += bv.w;
        *(f32x4*)&Y[(size_t)(row0 + q0 + qi) * M + c0] = o;
    }
}

// 2 queries per block. 256 threads = 8 heads x 32 lanes; lane owns 8 raw
// channels. Softmax in LDS, per-point {desc, 8 loads, fence, 32 FMA} gather,
// then fused W_val projection. No launch_bounds (see header comment).
#define QPB 2
__global__
void sample_agg_proj(const float* __restrict__ offs_all,
                     const float* __restrict__ logits_all,
                     const float* __restrict__ refpts,
                     const int* __restrict__ qoff, int n_off,
                     const float* __restrict__ v0, const float* __restrict__ v1,
                     const float* __restrict__ v2, const float* __restrict__ v3,
                     const float* __restrict__ W_val, const float* __restrict__ b_val,
                     float* __restrict__ val_out) {
    __shared__ float sOff[QPB][256];
    __shared__ float sAttn[QPB][128];
    __shared__ float sAgg[QPB][8][256];
    const int n0 = blockIdx.x * QPB;
    const int tid = threadIdx.x;

    if (tid < QPB * 64) ((f32x4*)sOff)[tid] = ((const f32x4*)(offs_all + (size_t)n0 * 256))[tid];
    else if (tid < QPB * 64 + QPB * 32)
        ((f32x4*)sAttn)[tid - QPB * 64] = ((const f32x4*)(logits_all + (size_t)n0 * 128))[tid - QPB * 64];
    __syncthreads();

    // softmax over 16 for each of QPB*8 (q,h) rows
    if (tid < QPB * 8) {
        float* row = &sAttn[tid >> 3][(tid & 7) * 16];
        float m = -1e30f;
#pragma unroll
        for (int i = 0; i < 16; ++i) m = fmaxf(m, row[i]);
        float s = 0.f;
#pragma unroll
        for (int i = 0; i < 16; ++i) { const float e = expf(row[i] - m); row[i] = e; s += e; }
        const float inv = 1.f / s;
#pragma unroll
        for (int i = 0; i < 16; ++i) row[i] *= inv;
    }
    __syncthreads();

    const int h = tid >> 5, g = tid & 31;
    const int g8 = g * 8;

    int b0 = 0, b1 = 0;
    for (int i = 1; i < n_off; ++i) {
        if (n0 >= qoff[i]) b0 = i;
        if (n0 + 1 >= qoff[i]) b1 = i;
    }
    const float4 rp = *(const float4*)(refpts + 2 * n0);  // n0 even -> aligned

    for (int q = 0; q < QPB; ++q) {
        const int b = (q == 0 ? b0 : b1);
        const float ri = (q == 0 ? rp.x : rp.z);
        const float rj = (q == 0 ? rp.y : rp.w);

        float acc[8];
#pragma unroll
        for (int j = 0; j < 8; ++j) acc[j] = 0.f;

#pragma unroll
        for (int l = 0; l < 4; ++l) {
            const int hw = (l == 0 ? 64 : (l == 1 ? 128 : (l == 2 ? 256 : 512)));
            const float sc = (float)hw * (1.0f / 512.0f);
            const float* vbl = (l == 0 ? v0 : (l == 1 ? v1 : (l == 2 ? v2 : v3)));
            const float* __restrict__ vb = vbl + (size_t)b * ((size_t)hw * hw * 256) + g8;

#pragma unroll
            for (int p = 0; p < 4; ++p) {
                // --- per-point descriptor (kept small & local) ---
                const int oi = ((h * 4 + l) * 4 + p) * 2;
                const float fi = (ri + sOff[q][oi]) * sc;
                const float fj = (rj + sOff[q][oi + 1]) * sc;
                const float a = sAttn[q][(h * 4 + l) * 4 + p];
                const float sci = fmaxf(fi - 0.5f, 0.f);
                const float scj = fmaxf(fj - 0.5f, 0.f);
                const float fl_i = floorf(sci), fl_j = floorf(scj);
                const int i0 = (int)fl_i, j0 = (int)fl_j;
                const float fri = sci - fl_i, frj = scj - fl_j;
                const int i0c = min(i0, hw - 1), i1c = min(i0 + 1, hw - 1);
                const int j0c = min(j0, hw - 1), j1c = min(j0 + 1, hw - 1);
                const float uw = 1.f - fri, lw = 1.f - frj;
                const float w00 = uw * lw * a, w01 = uw * frj * a;
                const float w10 = fri * lw * a, w11 = fri * frj * a;
                const float* r0 = vb + (size_t)i0c * hw * 256;
                const float* r1 = vb + (size_t)i1c * hw * 256;
                const f32x4* c00 = (const f32x4*)(r0 + (size_t)j0c * 256);
                const f32x4* c01 = (const f32x4*)(r0 + (size_t)j1c * 256);
                const f32x4* c10 = (const f32x4*)(r1 + (size_t)j0c * 256);
                const f32x4* c11 = (const f32x4*)(r1 + (size_t)j1c * 256);

                f32x4 buf[8];
                buf[0] = c00[0]; buf[1] = c00[1];
                buf[2] = c01[0]; buf[3] = c01[1];
                buf[4] = c10[0]; buf[5] = c10[1];
                buf[6] = c11[0]; buf[7] = c11[1];
                // Pin all 8 loads in flight; "memory" stops next-point loads
                // hoisting across (keeps register pressure bounded).
                asm volatile("" : "+v"(buf[0]), "+v"(buf[1]), "+v"(buf[2]), "+v"(buf[3]),
                                  "+v"(buf[4]), "+v"(buf[5]), "+v"(buf[6]), "+v"(buf[7])
                                :: "memory");
#pragma unroll
                for (int cr = 0; cr < 4; ++cr) {
                    const float wv = (cr == 0 ? w00 : (cr == 1 ? w01 : (cr == 2 ? w10 : w11)));
                    const f32x4 u = buf[cr * 2], x = buf[cr * 2 + 1];
                    acc[0] = fmaf(wv, u.x, acc[0]);
                    acc[1] = fmaf(wv, u.y, acc[1]);
                    acc[2] = fmaf(wv, u.z, acc[2]);
                    acc[3] = fmaf(wv, u.w, acc[3]);
                    acc[4] = fmaf(wv, x.x, acc[4]);
                    acc[5] = fmaf(wv, x.y, acc[5]);
                    acc[6] = fmaf(wv, x.z, acc[6]);
                    acc[7] = fmaf(wv, x.w, acc[7]);
                }
            }
        }

        f32x4* sa4 = (f32x4*)(&sAgg[q][h][g8]);
        sa4[0] = (f32x4){acc[0], acc[1], acc[2], acc[3]};
        sa4[1] = (f32x4){acc[4], acc[5], acc[6], acc[7]};
    }
    __syncthreads();

    // projection: out channel c2 = tid, head h2 = c2/32; W_val row loads
    // shared across the QPB queries.
    const int c2 = tid, h2 = tid >> 5;
    float s[QPB];
#pragma unroll
    for (int q = 0; q < QPB; ++q) s[q] = b_val[c2];
    for (int k4 = 0; k4 < 64; ++k4) {
        const float w0 = W_val[(k4 * 4 + 0) * 256 + c2];
        const float w1 = W_val[(k4 * 4 + 1) * 256 + c2];
        const float w2 = W_val[(k4 * 4 + 2) * 256 + c2];
        const float w3 = W_val[(k4 * 4 + 3) * 256 + c2];
#pragma unroll
        for (int q = 0; q < QPB; ++q) {
            const f32x4 av = ((const f32x4*)sAgg[q][h2])[k4];
            float t = s[q];
            t = fmaf(av.x, w0, t);
            t = fmaf(av.y, w1, t);
            t = fmaf(av.z, w2, t);
            t = fmaf(av.w, w3, t);
            s[q] = t;
        }
    }
#pragma unroll
    for (int q = 0; q < QPB; ++q)
        val_out[(size_t)(n0 + q) * 256 + c2] = s[q];
}

extern "C" void kernel_launch(void* const* d_in, const int* in_sizes, int n_in,
                              void* d_out, int out_size, void* d_ws, size_t ws_size,
                              hipStream_t stream) {
    const float* query  = (const float*)d_in[0];
    const int*   qoff   = (const int*)d_in[1];
    const float* refp   = (const float*)d_in[2];
    const float* v0     = (const float*)d_in[3];
    const float* v1     = (const float*)d_in[4];
    const float* v2     = (const float*)d_in[5];
    const float* v3     = (const float*)d_in[6];
    const float* W_off  = (const float*)d_in[7];
    const float* b_off  = (const float*)d_in[8];
    const float* W_attn = (const float*)d_in[9];
    const float* b_attn = (const float*)d_in[10];
    const float* W_val  = (const float*)d_in[11];
    const float* b_val  = (const float*)d_in[12];
    const float* W_out  = (const float*)d_in[13];
    const float* b_out  = (const float*)d_in[14];
    float* out = (float*)d_out;

    const int N = in_sizes[0] / 256;   // 16384
    const int n_off = in_sizes[1];     // 2

    float* P1off  = (float*)d_ws;                 // N*256 f32 (offsets)
    float* P1attn = P1off + (size_t)N * 256;      // N*128 f32 (attn logits)

    gemm_rb<256><<<N / 32, 256, 0, stream>>>(query, W_off, b_off, P1off);
    gemm_rb<128><<<N / 32, 128, 0, stream>>>(query, W_attn, b_attn, P1attn);
    // softmax fused into sample_agg_proj (reads logits).
    sample_agg_proj<<<N / QPB, 256, 0, stream>>>(P1off, P1attn, refp, qoff, n_off,
                                                 v0, v1, v2, v3, W_val, b_val, out);
    gemm_rb<256><<<N / 32, 256, 0, stream>>>(out, W_out, b_out, out);
}

// Round 9
// 598.960 us; speedup vs baseline: 8.1585x; 1.0261x over previous
//
#include <hip/hip_runtime.h>

// ---------------------------------------------------------------------------
// Sparse MS-Deformable Attention, f32.
// Round 9: SPATIAL QUERY REORDERING. Rounds 3/5/8 showed occupancy (43->65%)
// doesn't move the sampler (487/504/533 us): the bound is memory latency
// under RANDOM access order (queries are spatially random; 715 MB of maps
// thrash L2/L3; HBM floor would be ~170 us). Fix: bin queries by reference
// point (64x64 grid of 8px bins), process in bin-major order via a perm
// array, with XCD-chunked blockIdx swizzle so each XCD's concurrent blocks
// cover one compact spatial band -> corner rows shared through L2/L3.
// Sampler inner loop is byte-for-byte round 8's (spill-free, VGPR 40).
// ---------------------------------------------------------------------------

typedef float f32x4 __attribute__((ext_vector_type(4)));

// Y[n, 0:M] = X[n, 0:256] @ W[256, M] + bias ; 32 rows/block, M threads,
// thread tile = 8 queries x 4 cols. Safe in-place (Y==X).
template<int M>
__global__ __launch_bounds__(M)
void gemm_rb(const float* __restrict__ X, const float* __restrict__ W,
             const float* __restrict__ bias, float* __restrict__ Y) {
    __shared__ float xt[32 * 256];
    const int tid = threadIdx.x;
    const long row0 = (long)blockIdx.x * 32;
    const float4* src = (const float4*)(X + row0 * 256);
    float4* dst4 = (float4*)xt;
    for (int i = tid; i < 32 * 64; i += M) dst4[i] = src[i];
    __syncthreads();

    constexpr int CG = M / 4;
    const int cg = tid % CG, qg = tid / CG;
    const int c0 = cg * 4, q0 = qg * 8;

    f32x4 acc[8];
#pragma unroll
    for (int qi = 0; qi < 8; ++qi) acc[qi] = (f32x4){0.f, 0.f, 0.f, 0.f};

    for (int k4 = 0; k4 < 64; ++k4) {
        f32x4 w[4];
#pragma unroll
        for (int r = 0; r < 4; ++r)
            w[r] = *(const f32x4*)&W[(size_t)(k4 * 4 + r) * M + c0];
        f32x4 xv[8];
#pragma unroll
        for (int qi = 0; qi < 8; ++qi)
            xv[qi] = *(const f32x4*)&xt[(q0 + qi) * 256 + k4 * 4];
#pragma unroll
        for (int qi = 0; qi < 8; ++qi) {
            f32x4 a = acc[qi];
            const f32x4 x = xv[qi];
            a.x = fmaf(x.x, w[0].x, a.x); a.y = fmaf(x.x, w[0].y, a.y);
            a.z = fmaf(x.x, w[0].z, a.z); a.w = fmaf(x.x, w[0].w, a.w);
            a.x = fmaf(x.y, w[1].x, a.x); a.y = fmaf(x.y, w[1].y, a.y);
            a.z = fmaf(x.y, w[1].z, a.z); a.w = fmaf(x.y, w[1].w, a.w);
            a.x = fmaf(x.z, w[2].x, a.x); a.y = fmaf(x.z, w[2].y, a.y);
            a.z = fmaf(x.z, w[2].z, a.z); a.w = fmaf(x.z, w[2].w, a.w);
            a.x = fmaf(x.w, w[3].x, a.x); a.y = fmaf(x.w, w[3].y, a.y);
            a.z = fmaf(x.w, w[3].z, a.z); a.w = fmaf(x.w, w[3].w, a.w);
            acc[qi] = a;
        }
    }

    const f32x4 bv = *(const f32x4*)&bias[c0];
#pragma unroll
    for (int qi = 0; qi < 8; ++qi) {
        f32x4 o = acc[qi];
        o.x += bv.x; o.y += bv.y; o.z += bv.z; o.w += bv.w;
        *(f32x4*)&Y[(size_t)(row0 + q0 + qi) * M + c0] = o;
    }
}

// ---- spatial binning: 64x64 bins of 8x8 px over the 512x512 base frame ----
#define NBINS 4096

__device__ __forceinline__ int bin_of(float ri, float rj) {
    int bi = (int)ri >> 3, bj = (int)rj >> 3;
    bi = min(63, max(0, bi)); bj = min(63, max(0, bj));
    return bi * 64 + bj;
}

__global__ void bin_hist(const float* __restrict__ refp, int* __restrict__ hist, int N) {
    const int n = blockIdx.x * blockDim.x + threadIdx.x;
    if (n < N) atomicAdd(&hist[bin_of(refp[2 * n], refp[2 * n + 1])], 1);
}

// 1 block x 256 threads: exclusive prefix over 4096 bins.
__global__ __launch_bounds__(256)
void bin_scan(const int* __restrict__ hist, int* __restrict__ binptr) {
    __shared__ int part[256];
    const int t = threadIdx.x;
    int vals[16], excl[16], run = 0;
#pragma unroll
    for (int i = 0; i < 16; ++i) { vals[i] = hist[t * 16 + i]; }
#pragma unroll
    for (int i = 0; i < 16; ++i) { excl[i] = run; run += vals[i]; }
    part[t] = run;
    __syncthreads();
    int off = 0;
    for (int i = 0; i < t; ++i) off += part[i];
#pragma unroll
    for (int i = 0; i < 16; ++i) binptr[t * 16 + i] = off + excl[i];
}

__global__ void bin_scatter(const float* __restrict__ refp, int* __restrict__ binptr,
                            int* __restrict__ perm, int N) {
    const int n = blockIdx.x * blockDim.x + threadIdx.x;
    if (n < N) {
        const int b = bin_of(refp[2 * n], refp[2 * n + 1]);
        const int pos = atomicAdd(&binptr[b], 1);
        perm[pos] = n;
    }
}

// 2 queries per block (via perm). 256 threads = 8 heads x 32 lanes; lane owns
// 8 raw channels. Softmax in LDS, per-point {desc, 8 loads, fence, 32 FMA}
// gather, then fused W_val projection. No launch_bounds (round-8 lesson).
#define QPB 2
__global__
void sample_agg_proj(const float* __restrict__ offs_all,
                     const float* __restrict__ logits_all,
                     const float* __restrict__ refpts,
                     const int* __restrict__ qoff, int n_off,
                     const int* __restrict__ perm,
                     const float* __restrict__ v0, const float* __restrict__ v1,
                     const float* __restrict__ v2, const float* __restrict__ v3,
                     const float* __restrict__ W_val, const float* __restrict__ b_val,
                     float* __restrict__ val_out) {
    __shared__ float sOff[QPB][256];
    __shared__ float sAttn[QPB][128];
    __shared__ int   sQ[QPB];
    __shared__ float sAgg[QPB][8][256];
    const int tid = threadIdx.x;

    // XCD-chunked swizzle: concurrent blocks on one XCD = contiguous chunk
    // of the spatially-sorted order. gridDim.x = 8192, divisible by 8.
    const int bid = blockIdx.x;
    const int cpx = gridDim.x >> 3;
    const int swz = (bid & 7) * cpx + (bid >> 3);
    const int n0p = swz * QPB;

    if (tid < QPB) sQ[tid] = perm[n0p + tid];
    __syncthreads();
    const int nA = sQ[0], nB = sQ[1];

    if (tid < 64)       ((f32x4*)sOff[0])[tid]        = ((const f32x4*)(offs_all   + (size_t)nA * 256))[tid];
    else if (tid < 128) ((f32x4*)sOff[1])[tid - 64]   = ((const f32x4*)(offs_all   + (size_t)nB * 256))[tid - 64];
    else if (tid < 160) ((f32x4*)sAttn[0])[tid - 128] = ((const f32x4*)(logits_all + (size_t)nA * 128))[tid - 128];
    else if (tid < 192) ((f32x4*)sAttn[1])[tid - 160] = ((const f32x4*)(logits_all + (size_t)nB * 128))[tid - 160];
    __syncthreads();

    // softmax over 16 for each of QPB*8 (q,h) rows
    if (tid < QPB * 8) {
        float* row = &sAttn[tid >> 3][(tid & 7) * 16];
        float m = -1e30f;
#pragma unroll
        for (int i = 0; i < 16; ++i) m = fmaxf(m, row[i]);
        float s = 0.f;
#pragma unroll
        for (int i = 0; i < 16; ++i) { const float e = expf(row[i] - m); row[i] = e; s += e; }
        const float inv = 1.f / s;
#pragma unroll
        for (int i = 0; i < 16; ++i) row[i] *= inv;
    }
    __syncthreads();

    const int h = tid >> 5, g = tid & 31;
    const int g8 = g * 8;

    int b0 = 0, b1 = 0;
    for (int i = 1; i < n_off; ++i) {
        if (nA >= qoff[i]) b0 = i;
        if (nB >= qoff[i]) b1 = i;
    }
    const float riA = refpts[2 * nA], rjA = refpts[2 * nA + 1];
    const float riB = refpts[2 * nB], rjB = refpts[2 * nB + 1];

    for (int q = 0; q < QPB; ++q) {
        const int b = (q == 0 ? b0 : b1);
        const float ri = (q == 0 ? riA : riB);
        const float rj = (q == 0 ? rjA : rjB);

        float acc[8];
#pragma unroll
        for (int j = 0; j < 8; ++j) acc[j] = 0.f;

#pragma unroll
        for (int l = 0; l < 4; ++l) {
            const int hw = (l == 0 ? 64 : (l == 1 ? 128 : (l == 2 ? 256 : 512)));
            const float sc = (float)hw * (1.0f / 512.0f);
            const float* vbl = (l == 0 ? v0 : (l == 1 ? v1 : (l == 2 ? v2 : v3)));
            const float* __restrict__ vb = vbl + (size_t)b * ((size_t)hw * hw * 256) + g8;

#pragma unroll
            for (int p = 0; p < 4; ++p) {
                const int oi = ((h * 4 + l) * 4 + p) * 2;
                const float fi = (ri + sOff[q][oi]) * sc;
                const float fj = (rj + sOff[q][oi + 1]) * sc;
                const float a = sAttn[q][(h * 4 + l) * 4 + p];
                const float sci = fmaxf(fi - 0.5f, 0.f);
                const float scj = fmaxf(fj - 0.5f, 0.f);
                const float fl_i = floorf(sci), fl_j = floorf(scj);
                const int i0 = (int)fl_i, j0 = (int)fl_j;
                const float fri = sci - fl_i, frj = scj - fl_j;
                const int i0c = min(i0, hw - 1), i1c = min(i0 + 1, hw - 1);
                const int j0c = min(j0, hw - 1), j1c = min(j0 + 1, hw - 1);
                const float uw = 1.f - fri, lw = 1.f - frj;
                const float w00 = uw * lw * a, w01 = uw * frj * a;
                const float w10 = fri * lw * a, w11 = fri * frj * a;
                const float* r0 = vb + (size_t)i0c * hw * 256;
                const float* r1 = vb + (size_t)i1c * hw * 256;
                const f32x4* c00 = (const f32x4*)(r0 + (size_t)j0c * 256);
                const f32x4* c01 = (const f32x4*)(r0 + (size_t)j1c * 256);
                const f32x4* c10 = (const f32x4*)(r1 + (size_t)j0c * 256);
                const f32x4* c11 = (const f32x4*)(r1 + (size_t)j1c * 256);

                f32x4 buf[8];
                buf[0] = c00[0]; buf[1] = c00[1];
                buf[2] = c01[0]; buf[3] = c01[1];
                buf[4] = c10[0]; buf[5] = c10[1];
                buf[6] = c11[0]; buf[7] = c11[1];
                asm volatile("" : "+v"(buf[0]), "+v"(buf[1]), "+v"(buf[2]), "+v"(buf[3]),
                                  "+v"(buf[4]), "+v"(buf[5]), "+v"(buf[6]), "+v"(buf[7])
                                :: "memory");
#pragma unroll
                for (int cr = 0; cr < 4; ++cr) {
                    const float wv = (cr == 0 ? w00 : (cr == 1 ? w01 : (cr == 2 ? w10 : w11)));
                    const f32x4 u = buf[cr * 2], x = buf[cr * 2 + 1];
                    acc[0] = fmaf(wv, u.x, acc[0]);
                    acc[1] = fmaf(wv, u.y, acc[1]);
                    acc[2] = fmaf(wv, u.z, acc[2]);
                    acc[3] = fmaf(wv, u.w, acc[3]);
                    acc[4] = fmaf(wv, x.x, acc[4]);
                    acc[5] = fmaf(wv, x.y, acc[5]);
                    acc[6] = fmaf(wv, x.z, acc[6]);
                    acc[7] = fmaf(wv, x.w, acc[7]);
                }
            }
        }

        f32x4* sa4 = (f32x4*)(&sAgg[q][h][g8]);
        sa4[0] = (f32x4){acc[0], acc[1], acc[2], acc[3]};
        sa4[1] = (f32x4){acc[4], acc[5], acc[6], acc[7]};
    }
    __syncthreads();

    // projection: out channel c2 = tid, head h2 = c2/32.
    const int c2 = tid, h2 = tid >> 5;
    float s[QPB];
#pragma unroll
    for (int q = 0; q < QPB; ++q) s[q] = b_val[c2];
    for (int k4 = 0; k4 < 64; ++k4) {
        const float w0 = W_val[(k4 * 4 + 0) * 256 + c2];
        const float w1 = W_val[(k4 * 4 + 1) * 256 + c2];
        const float w2 = W_val[(k4 * 4 + 2) * 256 + c2];
        const float w3 = W_val[(k4 * 4 + 3) * 256 + c2];
#pragma unroll
        for (int q = 0; q < QPB; ++q) {
            const f32x4 av = ((const f32x4*)sAgg[q][h2])[k4];
            float t = s[q];
            t = fmaf(av.x, w0, t);
            t = fmaf(av.y, w1, t);
            t = fmaf(av.z, w2, t);
            t = fmaf(av.w, w3, t);
            s[q] = t;
        }
    }
    val_out[(size_t)nA * 256 + c2] = s[0];
    val_out[(size_t)nB * 256 + c2] = s[1];
}

extern "C" void kernel_launch(void* const* d_in, const int* in_sizes, int n_in,
                              void* d_out, int out_size, void* d_ws, size_t ws_size,
                              hipStream_t stream) {
    const float* query  = (const float*)d_in[0];
    const int*   qoff   = (const int*)d_in[1];
    const float* refp   = (const float*)d_in[2];
    const float* v0     = (const float*)d_in[3];
    const float* v1     = (const float*)d_in[4];
    const float* v2     = (const float*)d_in[5];
    const float* v3     = (const float*)d_in[6];
    const float* W_off  = (const float*)d_in[7];
    const float* b_off  = (const float*)d_in[8];
    const float* W_attn = (const float*)d_in[9];
    const float* b_attn = (const float*)d_in[10];
    const float* W_val  = (const float*)d_in[11];
    const float* b_val  = (const float*)d_in[12];
    const float* W_out  = (const float*)d_in[13];
    const float* b_out  = (const float*)d_in[14];
    float* out = (float*)d_out;

    const int N = in_sizes[0] / 256;   // 16384
    const int n_off = in_sizes[1];     // 2

    float* P1off  = (float*)d_ws;                    // N*256 f32
    float* P1attn = P1off + (size_t)N * 256;         // N*128 f32
    int*   hist   = (int*)(P1attn + (size_t)N * 128); // NBINS
    int*   binptr = hist + NBINS;                    // NBINS
    int*   perm   = binptr + NBINS;                  // N

    // spatial ordering (output is order-independent -> deterministic)
    hipMemsetAsync(hist, 0, NBINS * sizeof(int), stream);
    bin_hist<<<(N + 255) / 256, 256, 0, stream>>>(refp, hist, N);
    bin_scan<<<1, 256, 0, stream>>>(hist, binptr);
    bin_scatter<<<(N + 255) / 256, 256, 0, stream>>>(refp, binptr, perm, N);

    gemm_rb<256><<<N / 32, 256, 0, stream>>>(query, W_off, b_off, P1off);
    gemm_rb<128><<<N / 32, 128, 0, stream>>>(query, W_attn, b_attn, P1attn);
    sample_agg_proj<<<N / QPB, 256, 0, stream>>>(P1off, P1attn, refp, qoff, n_off,
                                                 perm, v0, v1, v2, v3, W_val, b_val, out);
    gemm_rb<256><<<N / 32, 256, 0, stream>>>(out, W_out, b_out, out);
}

// Round 10
// 582.755 us; speedup vs baseline: 8.3853x; 1.0278x over previous
//
#include <hip/hip_runtime.h>

// ---------------------------------------------------------------------------
// Sparse MS-Deformable Attention, f32.
// Round 10: ACCESS-SHAPE change in the sampler. Rounds 3..9 showed the gather
// is pinned at ~500 us (~17 TB/s L1-side) regardless of occupancy (43-65%),
// MLP depth, or HBM traffic (FETCH 1.0->0.62 GB did nothing). Old layout:
// wave = 2 heads = 2 pixels per instruction -> every dwordx4 splits into two
// unrelated 512B runs at the TA. New layout: one instruction = ONE contiguous
// 1KB pixel row (64 lanes x 4ch, dwordx4); wave handles its 2 heads
// sequentially (accA/accB f32x4 per lane). Same bytes, same instruction
// count, same fence-per-point structure, same sort/swizzle/projection.
// ---------------------------------------------------------------------------

typedef float f32x4 __attribute__((ext_vector_type(4)));

// Y[n, 0:M] = X[n, 0:256] @ W[256, M] + bias ; 32 rows/block, M threads,
// thread tile = 8 queries x 4 cols. Safe in-place (Y==X).
template<int M>
__global__ __launch_bounds__(M)
void gemm_rb(const float* __restrict__ X, const float* __restrict__ W,
             const float* __restrict__ bias, float* __restrict__ Y) {
    __shared__ float xt[32 * 256];
    const int tid = threadIdx.x;
    const long row0 = (long)blockIdx.x * 32;
    const float4* src = (const float4*)(X + row0 * 256);
    float4* dst4 = (float4*)xt;
    for (int i = tid; i < 32 * 64; i += M) dst4[i] = src[i];
    __syncthreads();

    constexpr int CG = M / 4;
    const int cg = tid % CG, qg = tid / CG;
    const int c0 = cg * 4, q0 = qg * 8;

    f32x4 acc[8];
#pragma unroll
    for (int qi = 0; qi < 8; ++qi) acc[qi] = (f32x4){0.f, 0.f, 0.f, 0.f};

    for (int k4 = 0; k4 < 64; ++k4) {
        f32x4 w[4];
#pragma unroll
        for (int r = 0; r < 4; ++r)
            w[r] = *(const f32x4*)&W[(size_t)(k4 * 4 + r) * M + c0];
        f32x4 xv[8];
#pragma unroll
        for (int qi = 0; qi < 8; ++qi)
            xv[qi] = *(const f32x4*)&xt[(q0 + qi) * 256 + k4 * 4];
#pragma unroll
        for (int qi = 0; qi < 8; ++qi) {
            f32x4 a = acc[qi];
            const f32x4 x = xv[qi];
            a.x = fmaf(x.x, w[0].x, a.x); a.y = fmaf(x.x, w[0].y, a.y);
            a.z = fmaf(x.x, w[0].z, a.z); a.w = fmaf(x.x, w[0].w, a.w);
            a.x = fmaf(x.y, w[1].x, a.x); a.y = fmaf(x.y, w[1].y, a.y);
            a.z = fmaf(x.y, w[1].z, a.z); a.w = fmaf(x.y, w[1].w, a.w);
            a.x = fmaf(x.z, w[2].x, a.x); a.y = fmaf(x.z, w[2].y, a.y);
            a.z = fmaf(x.z, w[2].z, a.z); a.w = fmaf(x.z, w[2].w, a.w);
            a.x = fmaf(x.w, w[3].x, a.x); a.y = fmaf(x.w, w[3].y, a.y);
            a.z = fmaf(x.w, w[3].z, a.z); a.w = fmaf(x.w, w[3].w, a.w);
            acc[qi] = a;
        }
    }

    const f32x4 bv = *(const f32x4*)&bias[c0];
#pragma unroll
    for (int qi = 0; qi < 8; ++qi) {
        f32x4 o = acc[qi];
        o.x += bv.x; o.y += bv.y; o.z += bv.z; o.w += bv.w;
        *(f32x4*)&Y[(size_t)(row0 + q0 + qi) * M + c0] = o;
    }
}

// ---- spatial binning: 64x64 bins of 8x8 px over the 512x512 base frame ----
#define NBINS 4096

__device__ __forceinline__ int bin_of(float ri, float rj) {
    int bi = (int)ri >> 3, bj = (int)rj >> 3;
    bi = min(63, max(0, bi)); bj = min(63, max(0, bj));
    return bi * 64 + bj;
}

__global__ void bin_hist(const float* __restrict__ refp, int* __restrict__ hist, int N) {
    const int n = blockIdx.x * blockDim.x + threadIdx.x;
    if (n < N) atomicAdd(&hist[bin_of(refp[2 * n], refp[2 * n + 1])], 1);
}

// 1 block x 256 threads: exclusive prefix over 4096 bins.
__global__ __launch_bounds__(256)
void bin_scan(const int* __restrict__ hist, int* __restrict__ binptr) {
    __shared__ int part[256];
    const int t = threadIdx.x;
    int vals[16], excl[16], run = 0;
#pragma unroll
    for (int i = 0; i < 16; ++i) { vals[i] = hist[t * 16 + i]; }
#pragma unroll
    for (int i = 0; i < 16; ++i) { excl[i] = run; run += vals[i]; }
    part[t] = run;
    __syncthreads();
    int off = 0;
    for (int i = 0; i < t; ++i) off += part[i];
#pragma unroll
    for (int i = 0; i < 16; ++i) binptr[t * 16 + i] = off + excl[i];
}

__global__ void bin_scatter(const float* __restrict__ refp, int* __restrict__ binptr,
                            int* __restrict__ perm, int N) {
    const int n = blockIdx.x * blockDim.x + threadIdx.x;
    if (n < N) {
        const int b = bin_of(refp[2 * n], refp[2 * n + 1]);
        const int pos = atomicAdd(&binptr[b], 1);
        perm[pos] = n;
    }
}

// 2 queries per block (via perm). 256 threads = 4 waves; each wave owns 2
// heads. Per sample point: whole wave loads each corner pixel as one
// contiguous 1KB dwordx4 instruction (lane c owns channels 4c..4c+3).
// Softmax in LDS, per-point {desc x2 heads, 8 loads, fence, 32 FMA} gather,
// then fused W_val projection. No launch_bounds (round-8 lesson).
#define QPB 2
__global__
void sample_agg_proj(const float* __restrict__ offs_all,
                     const float* __restrict__ logits_all,
                     const float* __restrict__ refpts,
                     const int* __restrict__ qoff, int n_off,
                     const int* __restrict__ perm,
                     const float* __restrict__ v0, const float* __restrict__ v1,
                     const float* __restrict__ v2, const float* __restrict__ v3,
                     const float* __restrict__ W_val, const float* __restrict__ b_val,
                     float* __restrict__ val_out) {
    __shared__ float sOff[QPB][256];
    __shared__ float sAttn[QPB][128];
    __shared__ int   sQ[QPB];
    __shared__ float sAgg[QPB][8][256];
    const int tid = threadIdx.x;

    // XCD-chunked swizzle over the spatially-sorted order (grid = 8192, %8==0)
    const int bid = blockIdx.x;
    const int cpx = gridDim.x >> 3;
    const int swz = (bid & 7) * cpx + (bid >> 3);
    const int n0p = swz * QPB;

    if (tid < QPB) sQ[tid] = perm[n0p + tid];
    __syncthreads();
    const int nA = sQ[0], nB = sQ[1];

    if (tid < 64)       ((f32x4*)sOff[0])[tid]        = ((const f32x4*)(offs_all   + (size_t)nA * 256))[tid];
    else if (tid < 128) ((f32x4*)sOff[1])[tid - 64]   = ((const f32x4*)(offs_all   + (size_t)nB * 256))[tid - 64];
    else if (tid < 160) ((f32x4*)sAttn[0])[tid - 128] = ((const f32x4*)(logits_all + (size_t)nA * 128))[tid - 128];
    else if (tid < 192) ((f32x4*)sAttn[1])[tid - 160] = ((const f32x4*)(logits_all + (size_t)nB * 128))[tid - 160];
    __syncthreads();

    // softmax over 16 for each of QPB*8 (q,h) rows
    if (tid < QPB * 8) {
        float* row = &sAttn[tid >> 3][(tid & 7) * 16];
        float m = -1e30f;
#pragma unroll
        for (int i = 0; i < 16; ++i) m = fmaxf(m, row[i]);
        float s = 0.f;
#pragma unroll
        for (int i = 0; i < 16; ++i) { const float e = expf(row[i] - m); row[i] = e; s += e; }
        const float inv = 1.f / s;
#pragma unroll
        for (int i = 0; i < 16; ++i) row[i] *= inv;
    }
    __syncthreads();

    const int wave = tid >> 6, lane = tid & 63;
    const int h0 = wave << 1;

    int b0 = 0, b1 = 0;
    for (int i = 1; i < n_off; ++i) {
        if (nA >= qoff[i]) b0 = i;
        if (nB >= qoff[i]) b1 = i;
    }
    const float riA = refpts[2 * nA], rjA = refpts[2 * nA + 1];
    const float riB = refpts[2 * nB], rjB = refpts[2 * nB + 1];

    for (int q = 0; q < QPB; ++q) {
        const int b = (q == 0 ? b0 : b1);
        const float ri = (q == 0 ? riA : riB);
        const float rj = (q == 0 ? rjA : rjB);

        f32x4 accA = (f32x4){0.f, 0.f, 0.f, 0.f};
        f32x4 accB = (f32x4){0.f, 0.f, 0.f, 0.f};

#pragma unroll
        for (int l = 0; l < 4; ++l) {
            const int hw = (l == 0 ? 64 : (l == 1 ? 128 : (l == 2 ? 256 : 512)));
            const float sc = (float)hw * (1.0f / 512.0f);
            const float* vbl = (l == 0 ? v0 : (l == 1 ? v1 : (l == 2 ? v2 : v3)));
            const float* __restrict__ vb = vbl + (size_t)b * ((size_t)hw * hw * 256);

#pragma unroll
            for (int p = 0; p < 4; ++p) {
                int   o[8];     // 2 heads x 4 corner pixel offsets (floats)
                float wgt[8];   // matching attn-scaled bilinear weights
#pragma unroll
                for (int hh = 0; hh < 2; ++hh) {
                    const int h_ = h0 + hh;
                    const int oi = ((h_ * 4 + l) * 4 + p) * 2;
                    const float fi = (ri + sOff[q][oi]) * sc;
                    const float fj = (rj + sOff[q][oi + 1]) * sc;
                    const float a = sAttn[q][(h_ * 4 + l) * 4 + p];
                    const float sci = fmaxf(fi - 0.5f, 0.f);
                    const float scj = fmaxf(fj - 0.5f, 0.f);
                    const float fl_i = floorf(sci), fl_j = floorf(scj);
                    const int i0 = (int)fl_i, j0 = (int)fl_j;
                    const float fri = sci - fl_i, frj = scj - fl_j;
                    const int i0c = min(i0, hw - 1), i1c = min(i0 + 1, hw - 1);
                    const int j0c = min(j0, hw - 1), j1c = min(j0 + 1, hw - 1);
                    const float uw = 1.f - fri, lw = 1.f - frj;
                    o[hh * 4 + 0] = (i0c * hw + j0c) << 8;
                    o[hh * 4 + 1] = (i0c * hw + j1c) << 8;
                    o[hh * 4 + 2] = (i1c * hw + j0c) << 8;
                    o[hh * 4 + 3] = (i1c * hw + j1c) << 8;
                    wgt[hh * 4 + 0] = uw * lw * a;
                    wgt[hh * 4 + 1] = uw * frj * a;
                    wgt[hh * 4 + 2] = fri * lw * a;
                    wgt[hh * 4 + 3] = fri * frj * a;
                }

                f32x4 buf[8];
#pragma unroll
                for (int k = 0; k < 8; ++k)
                    buf[k] = ((const f32x4*)(vb + o[k]))[lane];   // 1KB contiguous/instr
                asm volatile("" : "+v"(buf[0]), "+v"(buf[1]), "+v"(buf[2]), "+v"(buf[3]),
                                  "+v"(buf[4]), "+v"(buf[5]), "+v"(buf[6]), "+v"(buf[7])
                                :: "memory");
#pragma unroll
                for (int k = 0; k < 8; ++k) {
                    const float wv = wgt[k];
                    if (k < 4) {
                        accA[0] = fmaf(wv, buf[k][0], accA[0]);
                        accA[1] = fmaf(wv, buf[k][1], accA[1]);
                        accA[2] = fmaf(wv, buf[k][2], accA[2]);
                        accA[3] = fmaf(wv, buf[k][3], accA[3]);
                    } else {
                        accB[0] = fmaf(wv, buf[k][0], accB[0]);
                        accB[1] = fmaf(wv, buf[k][1], accB[1]);
                        accB[2] = fmaf(wv, buf[k][2], accB[2]);
                        accB[3] = fmaf(wv, buf[k][3], accB[3]);
                    }
                }
            }
        }

        ((f32x4*)sAgg[q][h0 + 0])[lane] = accA;
        ((f32x4*)sAgg[q][h0 + 1])[lane] = accB;
    }
    __syncthreads();

    // projection: out channel c2 = tid, head h2 = c2/32.
    const int c2 = tid, h2 = tid >> 5;
    float s[QPB];
#pragma unroll
    for (int q = 0; q < QPB; ++q) s[q] = b_val[c2];
    for (int k4 = 0; k4 < 64; ++k4) {
        const float w0 = W_val[(k4 * 4 + 0) * 256 + c2];
        const float w1 = W_val[(k4 * 4 + 1) * 256 + c2];
        const float w2 = W_val[(k4 * 4 + 2) * 256 + c2];
        const float w3 = W_val[(k4 * 4 + 3) * 256 + c2];
#pragma unroll
        for (int q = 0; q < QPB; ++q) {
            const f32x4 av = ((const f32x4*)sAgg[q][h2])[k4];
            float t = s[q];
            t = fmaf(av.x, w0, t);
            t = fmaf(av.y, w1, t);
            t = fmaf(av.z, w2, t);
            t = fmaf(av.w, w3, t);
            s[q] = t;
        }
    }
    val_out[(size_t)nA * 256 + c2] = s[0];
    val_out[(size_t)nB * 256 + c2] = s[1];
}

extern "C" void kernel_launch(void* const* d_in, const int* in_sizes, int n_in,
                              void* d_out, int out_size, void* d_ws, size_t ws_size,
                              hipStream_t stream) {
    const float* query  = (const float*)d_in[0];
    const int*   qoff   = (const int*)d_in[1];
    const float* refp   = (const float*)d_in[2];
    const float* v0     = (const float*)d_in[3];
    const float* v1     = (const float*)d_in[4];
    const float* v2     = (const float*)d_in[5];
    const float* v3     = (const float*)d_in[6];
    const float* W_off  = (const float*)d_in[7];
    const float* b_off  = (const float*)d_in[8];
    const float* W_attn = (const float*)d_in[9];
    const float* b_attn = (const float*)d_in[10];
    const float* W_val  = (const float*)d_in[11];
    const float* b_val  = (const float*)d_in[12];
    const float* W_out  = (const float*)d_in[13];
    const float* b_out  = (const float*)d_in[14];
    float* out = (float*)d_out;

    const int N = in_sizes[0] / 256;   // 16384
    const int n_off = in_sizes[1];     // 2

    float* P1off  = (float*)d_ws;                    // N*256 f32
    float* P1attn = P1off + (size_t)N * 256;         // N*128 f32
    int*   hist   = (int*)(P1attn + (size_t)N * 128); // NBINS
    int*   binptr = hist + NBINS;                    // NBINS
    int*   perm   = binptr + NBINS;                  // N

    // spatial ordering (output is order-independent -> deterministic)
    hipMemsetAsync(hist, 0, NBINS * sizeof(int), stream);
    bin_hist<<<(N + 255) / 256, 256, 0, stream>>>(refp, hist, N);
    bin_scan<<<1, 256, 0, stream>>>(hist, binptr);
    bin_scatter<<<(N + 255) / 256, 256, 0, stream>>>(refp, binptr, perm, N);

    gemm_rb<256><<<N / 32, 256, 0, stream>>>(query, W_off, b_off, P1off);
    gemm_rb<128><<<N / 32, 128, 0, stream>>>(query, W_attn, b_attn, P1attn);
    sample_agg_proj<<<N / QPB, 256, 0, stream>>>(P1off, P1attn, refp, qoff, n_off,
                                                 perm, v0, v1, v2, v3, W_val, b_val, out);
    gemm_rb<256><<<N / 32, 256, 0, stream>>>(out, W_out, b_out, out);
}